// Round 1
// baseline (232.399 us; speedup 1.0000x reference)
//
#include <hip/hip_runtime.h>
#include <hip/hip_bf16.h>

#define HM_W 512
#define HM_H 512
#define PW   508   // 512 - 5 + 1

__device__ __forceinline__ void row_colsums(const float* hm, int r, float* colbuf,
                                            const int* zr, const int* zc, int cnt, int lane) {
    int c0 = lane * 8;
    float s[8];
#pragma unroll
    for (int j = 0; j < 8; ++j) s[j] = 0.f;
#pragma unroll
    for (int i = 0; i < 5; ++i) {
        int y = r + i; y = y > (HM_H - 1) ? (HM_H - 1) : y;
        const float4* rp = reinterpret_cast<const float4*>(hm + y * HM_W + c0);
        float4 a = rp[0];
        float4 b = rp[1];
        float v[8] = {a.x, a.y, a.z, a.w, b.x, b.y, b.z, b.w};
#pragma unroll
        for (int j = 0; j < 8; ++j) {
            float vv = v[j];
#pragma unroll
            for (int k = 0; k < 6; ++k) {
                if (k < cnt && (unsigned)(y - zr[k]) < 5u && (unsigned)(c0 + j - zc[k]) < 5u)
                    vv = 0.f;
            }
            s[j] += vv;
        }
    }
#pragma unroll
    for (int j = 0; j < 8; ++j) colbuf[c0 + j] = s[j];
}

// Per-lane window sums over this wave's row, then wave-wide argmax
// (tie-break: lowest column). All 64 lanes end with the reduced result.
__device__ __forceinline__ void row_window_best(const float* colbuf, int lane,
                                                float& bv, int& bc) {
    int c0 = lane * 8;
    float cb[12];
#pragma unroll
    for (int j = 0; j < 12; ++j) cb[j] = colbuf[c0 + j];
    bv = -__builtin_inff();
    bc = 0x7fffffff;
#pragma unroll
    for (int j = 0; j < 8; ++j) {
        int c = c0 + j;
        float s = cb[j] + cb[j + 1] + cb[j + 2] + cb[j + 3] + cb[j + 4];
        if (c < PW && s > bv) { bv = s; bc = c; }   // ascending c => keeps lowest c on ties
    }
#pragma unroll
    for (int m = 1; m < 64; m <<= 1) {
        float ov = __shfl_xor(bv, m);
        int   oc = __shfl_xor(bc, m);
        if (ov > bv || (ov == bv && oc < bc)) { bv = ov; bc = oc; }
    }
}

// Phase 1: per-row argmax of the 5x5 box-sum for all rows, all batches.
// One wave handles 4 consecutive aggregate rows. grid = (32, 128), block = 256.
__global__ void phase1_kernel(const float* __restrict__ hm_all,
                              float* __restrict__ rowv_ws, int* __restrict__ rowc_ws) {
    int b = blockIdx.y;
    int wave = threadIdx.x >> 6;
    int lane = threadIdx.x & 63;
    const float* hm = hm_all + (size_t)b * HM_W * HM_H;
    __shared__ float colbuf[4][520];

    int rbase = (blockIdx.x * 4 + wave) * 4;
#pragma unroll
    for (int j = 0; j < 4; ++j) {
        int r = rbase + j;
        int rcl = r > (PW - 1) ? (PW - 1) : r;
        row_colsums(hm, rcl, colbuf[wave], nullptr, nullptr, 0, lane);
        __syncthreads();
        float bv; int bc;
        row_window_best(colbuf[wave], lane, bv, bc);
        if (lane == 0 && r < PW) {
            rowv_ws[b * 512 + r] = bv;
            rowc_ws[b * 512 + r] = bc;
        }
        __syncthreads();
    }
}

// Phase 2: per batch, 6 sequential peak-extractions with incremental row updates.
// grid = 128, block = 256 (4 waves).
__global__ void phase2_kernel(const float* __restrict__ hm_all,
                              const float* __restrict__ rowv_ws,
                              const int* __restrict__ rowc_ws,
                              int* __restrict__ out) {
    int b = blockIdx.x;
    const float* hm = hm_all + (size_t)b * HM_W * HM_H;
    int t = threadIdx.x;
    int wave = t >> 6, lane = t & 63;

    __shared__ float rowv[512];
    __shared__ int   rowc[512];
    __shared__ float colbuf[4][520];
    __shared__ float rv[4];
    __shared__ int   rr[4], rc[4];
    __shared__ int   zr[8], zc[8];
    __shared__ int   bcastR;

    for (int i = t; i < 512; i += 256) {
        if (i < PW) { rowv[i] = rowv_ws[b * 512 + i]; rowc[i] = rowc_ws[b * 512 + i]; }
        else        { rowv[i] = -__builtin_inff();    rowc[i] = 0; }
    }
    __syncthreads();

    for (int it = 0; it < 6; ++it) {
        // ---- block-wide argmax over 508 row maxima (tie-break lowest row) ----
        float v1 = rowv[t], v2 = rowv[t + 256];
        float bv; int br;
        if (v2 > v1) { bv = v2; br = t + 256; } else { bv = v1; br = t; }
        int bc = rowc[br];
#pragma unroll
        for (int m = 1; m < 64; m <<= 1) {
            float ov = __shfl_xor(bv, m);
            int   orr = __shfl_xor(br, m);
            int   oc = __shfl_xor(bc, m);
            if (ov > bv || (ov == bv && orr < br)) { bv = ov; br = orr; bc = oc; }
        }
        if (lane == 0) { rv[wave] = bv; rr[wave] = br; rc[wave] = bc; }
        __syncthreads();
        if (t == 0) {
            float fv = rv[0]; int fr = rr[0], fc = rc[0];
#pragma unroll
            for (int w = 1; w < 4; ++w) {
                if (rv[w] > fv || (rv[w] == fv && rr[w] < fr)) { fv = rv[w]; fr = rr[w]; fc = rc[w]; }
            }
            bcastR = fr;
            zr[it] = fr; zc[it] = fc;
            out[b * 12 + it * 2 + 0] = fc + 2;   // SWAP_RC: (c+R, r+R)
            out[b * 12 + it * 2 + 1] = fr + 2;
        }
        __syncthreads();

        // ---- recompute the <=9 affected rows with the zero-block mask ----
        int R  = bcastR;
        int y0 = R - 4 < 0 ? 0 : R - 4;
        int y1 = R + 4 > (PW - 1) ? (PW - 1) : R + 4;
        int cnt = it + 1;
#pragma unroll
        for (int s = 0; s < 3; ++s) {
            int y = y0 + s * 4 + wave;
            bool active = (y <= y1);
            int yy = active ? y : y0;
            row_colsums(hm, yy, colbuf[wave], zr, zc, cnt, lane);
            __syncthreads();
            float nv; int nc;
            row_window_best(colbuf[wave], lane, nv, nc);
            if (active && lane == 0) { rowv[y] = nv; rowc[y] = nc; }
            __syncthreads();
        }
    }
}

extern "C" void kernel_launch(void* const* d_in, const int* in_sizes, int n_in,
                              void* d_out, int out_size, void* d_ws, size_t ws_size,
                              hipStream_t stream) {
    const float* hm = (const float*)d_in[0];
    int* out = (int*)d_out;
    float* rowv_ws = (float*)d_ws;
    int*   rowc_ws = (int*)((char*)d_ws + (size_t)128 * 512 * sizeof(float));

    phase1_kernel<<<dim3(32, 128), dim3(256), 0, stream>>>(hm, rowv_ws, rowc_ws);
    phase2_kernel<<<dim3(128), dim3(256), 0, stream>>>(hm, rowv_ws, rowc_ws, out);
}

// Round 2
// 56.129 us; speedup vs baseline: 4.1405x; 4.1405x over previous
//
#include <hip/hip_runtime.h>
#include <hip/hip_bf16.h>

#define HM_W 512
#define HM_H 512
#define PW   508   // 512 - 5 + 1

__device__ __forceinline__ void load_row8(const float* __restrict__ hm, int y, int c0, float v[8]) {
    const float4* rp = reinterpret_cast<const float4*>(hm + y * HM_W + c0);
    float4 a = rp[0];
    float4 b = rp[1];
    v[0]=a.x; v[1]=a.y; v[2]=a.z; v[3]=a.w;
    v[4]=b.x; v[5]=b.y; v[6]=b.z; v[7]=b.w;
}

// Per-lane 5-wide window sums from per-lane colsums s[0..7] (cols lane*8..lane*8+7),
// cross-lane tail via shfl, then wave-wide argmax (tie-break lowest col).
// Whole wave must be active. All lanes end with the result.
__device__ __forceinline__ void row_best_shfl(const float s[8], int lane, float& bv, int& bc) {
    float cb[12];
#pragma unroll
    for (int j = 0; j < 8; ++j) cb[j] = s[j];
#pragma unroll
    for (int j = 0; j < 4; ++j) cb[8 + j] = __shfl_down(s[j], 1);
    bv = -__builtin_inff();
    bc = 0x7fffffff;
    int c0 = lane * 8;
#pragma unroll
    for (int j = 0; j < 8; ++j) {
        int c = c0 + j;
        float w = cb[j] + cb[j + 1] + cb[j + 2] + cb[j + 3] + cb[j + 4];
        if (c < PW && w > bv) { bv = w; bc = c; }   // ascending c keeps lowest col on tie
    }
#pragma unroll
    for (int m = 1; m < 64; m <<= 1) {
        float ov = __shfl_xor(bv, m);
        int   oc = __shfl_xor(bc, m);
        if (ov > bv || (ov == bv && oc < bc)) { bv = ov; bc = oc; }
    }
}

// Phase 1: per-row argmax of the 5x5 box-sum, rolling 5-row register window.
// Each wave produces 16 aggregate rows from 20 input-row loads (1.25x redundancy).
// grid = (8, 128), block = 256 (4 waves). No LDS, no barriers.
__global__ void phase1_kernel(const float* __restrict__ hm_all,
                              float* __restrict__ rowv_ws, int* __restrict__ rowc_ws) {
    int b = blockIdx.y;
    int wave = threadIdx.x >> 6;
    int lane = threadIdx.x & 63;
    int c0 = lane * 8;
    const float* hm = hm_all + (size_t)b * HM_W * HM_H;

    int rbase = (blockIdx.x * 4 + wave) * 16;
    if (rbase >= PW) return;

    float w0[8], w1[8], w2[8], w3[8], w4[8];
    load_row8(hm, rbase + 0, c0, w0);
    load_row8(hm, rbase + 1, c0, w1);
    load_row8(hm, rbase + 2, c0, w2);
    load_row8(hm, rbase + 3, c0, w3);

#pragma unroll
    for (int rr = 0; rr < 16; ++rr) {
        int y = rbase + rr;
        if (y >= PW) break;                 // wave-uniform
        load_row8(hm, y + 4, c0, w4);
        float s[8];
#pragma unroll
        for (int j = 0; j < 8; ++j)
            s[j] = ((((w0[j] + w1[j]) + w2[j]) + w3[j]) + w4[j]);  // same order as 0+=v chain
        float bv; int bc;
        row_best_shfl(s, lane, bv, bc);
        if (lane == 0) {
            rowv_ws[b * 512 + y] = bv;
            rowc_ws[b * 512 + y] = bc;
        }
#pragma unroll
        for (int j = 0; j < 8; ++j) { w0[j] = w1[j]; w1[j] = w2[j]; w2[j] = w3[j]; w3[j] = w4[j]; }
    }
}

// Phase 2: per batch, 6 sequential peak extractions with single-step parallel
// row repair. grid = 128, block = 1024 (16 waves). 2 barriers per iteration.
__global__ void __launch_bounds__(1024) phase2_kernel(const float* __restrict__ hm_all,
                              const float* __restrict__ rowv_ws,
                              const int* __restrict__ rowc_ws,
                              int* __restrict__ out) {
    int b = blockIdx.x;
    const float* hm = hm_all + (size_t)b * HM_W * HM_H;
    int t = threadIdx.x;
    int wave = t >> 6, lane = t & 63;
    int c0 = lane * 8;

    __shared__ float rowv[512];
    __shared__ int   rowc[512];

    if (t < 512) {
        if (t < PW) { rowv[t] = rowv_ws[b * 512 + t]; rowc[t] = rowc_ws[b * 512 + t]; }
        else        { rowv[t] = -__builtin_inff();    rowc[t] = 0; }
    }

    int zrr[6], zcc[6];

#pragma unroll
    for (int it = 0; it < 6; ++it) {
        __syncthreads();   // (A) rowv/rowc stable from previous iteration's writes

        // ---- every wave redundantly computes the block argmax (tie: lowest row) ----
        float bv = -__builtin_inff(); int bi = 0x7fffffff;
#pragma unroll
        for (int j = 0; j < 8; ++j) {
            int idx = j * 64 + lane;       // stride-64: conflict-free, ascending idx per lane
            float v = rowv[idx];
            if (v > bv) { bv = v; bi = idx; }
        }
#pragma unroll
        for (int m = 1; m < 64; m <<= 1) {
            float ov = __shfl_xor(bv, m);
            int   oi = __shfl_xor(bi, m);
            if (ov > bv || (ov == bv && oi < bi)) { bv = ov; bi = oi; }
        }
        int fr = bi;
        int fc = rowc[fr];                 // same addr across lanes: broadcast
        zrr[it] = fr; zcc[it] = fc;        // kept in registers by every thread
        if (t == 0) {
            out[b * 12 + it * 2 + 0] = fc + 2;   // SWAP_RC: (c+R, r+R)
            out[b * 12 + it * 2 + 1] = fr + 2;
        }
        if (it == 5) break;                // last peak: no repair needed (compile-time)

        __syncthreads();   // (B) all argmax reads done before repair writes

        // ---- repair the <=9 affected rows, one wave each, in parallel ----
        int y0 = fr - 4 < 0 ? 0 : fr - 4;
        int y1 = fr + 4 > PW - 1 ? PW - 1 : fr + 4;
        int y  = y0 + wave;                // wave-uniform condition below
        if (wave < 9 && y <= y1) {
            float s[8];
#pragma unroll
            for (int j = 0; j < 8; ++j) s[j] = 0.f;
#pragma unroll
            for (int i = 0; i < 5; ++i) {
                float v[8];
                load_row8(hm, y + i, c0, v);
#pragma unroll
                for (int j = 0; j < 8; ++j) {
                    float vv = v[j];
#pragma unroll
                    for (int k = 0; k < 6; ++k) {
                        if (k <= it && (unsigned)(y + i - zrr[k]) < 5u
                                    && (unsigned)(c0 + j - zcc[k]) < 5u)
                            vv = 0.f;
                    }
                    s[j] += vv;
                }
            }
            float nv; int nc;
            row_best_shfl(s, lane, nv, nc);
            if (lane == 0) { rowv[y] = nv; rowc[y] = nc; }
        }
    }
}

extern "C" void kernel_launch(void* const* d_in, const int* in_sizes, int n_in,
                              void* d_out, int out_size, void* d_ws, size_t ws_size,
                              hipStream_t stream) {
    const float* hm = (const float*)d_in[0];
    int* out = (int*)d_out;
    float* rowv_ws = (float*)d_ws;
    int*   rowc_ws = (int*)((char*)d_ws + (size_t)128 * 512 * sizeof(float));

    phase1_kernel<<<dim3(8, 128), dim3(256), 0, stream>>>(hm, rowv_ws, rowc_ws);
    phase2_kernel<<<dim3(128), dim3(1024), 0, stream>>>(hm, rowv_ws, rowc_ws, out);
}